// Round 1
// baseline (333.205 us; speedup 1.0000x reference)
//
#include <hip/hip_runtime.h>
#include <hip/hip_bf16.h>
#include <cmath>

// LinearAttention: x[4,4096,1024] fp32 -> qkv -> elu+1 linear attention (16 heads, d=64) -> out proj.
// I/O fp32; internal bf16 MFMA w/ fp32 accum.
// Round 6: GEMMs rebuilt on the 256x256 8-phase counted-vmcnt schedule (T2+T3+T4+T5):
//   512 thr = 8 waves (2M x 4N), BK=64, LDS 128KiB = 2 buffers x 4 regions x 16KiB.
//   Regions: 0=B rows0-127, 1=B rows128-255, 2=A(mfrags0-3: rows 0-63 & 128-191),
//            3=A(mfrags4-7: rows 64-127 & 192-255).
//   Phase j of tile t: ds_read A-frag pair {2j,2j+1} (+ all B frags at j=0, held in regs),
//   stage one half-tile (phase0 -> next-tile region3 in other buffer; phases1-3 ->
//   tile t+2 regions 0,1,2 into the CURRENT buffer -- safe: those regions' reads
//   completed >=1 barrier earlier), vmcnt(6) once per tile (3 half-tiles in flight).
// Pipeline:
//   0) cvt x->xb, w_qkv->wqkvb, w_out->woutb (bf16)
//   1) gemm_bt<0>: qkv = xb @ wqkvb^T; epilogue q->feat*scale->Q[b,h,n,d], k->KT[b,h,d,n], v->VT
//   2) kv_partial: kvp[hh][ksp][e][d] = sum_n v[n,e] k[n,d]; ksp[hh][ksp][d] = sum_n k[n,d]
//   3) kvfix: kvb[hh][e][d] (bf16) = sum_ksp kvp; ksumb[hh][d] (bf16) = sum_ksp ksp
//   4) attn_out: att = (q @ kv) / (q . ksum + eps), denom via extra MFMA column
//   5) gemm_bt<1>: y = att @ woutb^T + b_out (fp32 out)

typedef __bf16 bf16_t;
typedef __attribute__((ext_vector_type(8))) __bf16 bf16x8;
typedef __attribute__((ext_vector_type(4))) __bf16 bf16x4;
typedef __attribute__((ext_vector_type(4))) float f32x4;
typedef __attribute__((ext_vector_type(8))) float f32x8;

#define MFMA16(a, b, c) __builtin_amdgcn_mfma_f32_16x16x32_bf16((a), (b), (c), 0, 0, 0)

#define LDS_PITCH 72  // padded pitch for the simple-staging (non-GEMM) kernels

__device__ __forceinline__ f32x4 zf4() { f32x4 z; z[0] = 0.f; z[1] = 0.f; z[2] = 0.f; z[3] = 0.f; return z; }

__device__ __forceinline__ float feat(float x) { return x > 0.f ? x + 1.f : expf(x); }

// ---------------- async staging primitive ----------------
__device__ __forceinline__ void gld_lds16(const bf16_t* src, bf16_t* dst)
{
    __builtin_amdgcn_global_load_lds(
        (__attribute__((address_space(1))) void*)const_cast<bf16_t*>(src),
        (__attribute__((address_space(3))) void*)dst, 16, 0, 0);
}

// ---------------- 256x256 8-phase GEMM staging ----------------
// One region = 128 rows x 64 bf16 (16 KiB), XOR-swizzled by granule: LDS granule (rr,p)
// holds global granule (rr, p ^ (rr&7)). 512 threads, 2 global_load_lds per wave.
template <int R>
__device__ __forceinline__ void stage_region(const bf16_t* Ab, const bf16_t* Bb, int K,
                                             int koff, bf16_t* buf, int tid)
{
    const int w = tid >> 6, l = tid & 63;
    bf16_t* dst = buf + R * 8192;
#pragma unroll
    for (int p = 0; p < 2; ++p) {
        const int chunk = w * 2 + p;          // wave-uniform, 0..15
        const int gidx = chunk * 64 + l;      // granule 0..1023
        const int rr = gidx >> 3;             // region row 0..127
        const int c = (gidx & 7) ^ (rr & 7);  // pre-swizzled source granule
        const bf16_t* src;
        if (R == 0)      src = Bb + (size_t)rr * K;                 // B rows 0..127
        else if (R == 1) src = Bb + (size_t)(128 + rr) * K;         // B rows 128..255
        else if (R == 2) src = Ab + (size_t)(rr + (rr & 64)) * K;   // A rows 0..63,128..191
        else             src = Ab + (size_t)(64 + rr + (rr & 64)) * K; // A rows 64..127,192..255
        gld_lds16(src + koff + c * 8, dst + chunk * 512);
    }
}

// Fragment read from a swizzled region (64-elem pitch): 2-way LDS aliasing only (free, m136).
__device__ __forceinline__ bf16x8 rfrag(const bf16_t* region, int rr, int cg)
{
    const int sw = cg ^ (rr & 7);
    return *(const bf16x8*)(region + rr * 64 + sw * 8);
}

// ---------------- simple staging (middle kernels) ----------------
template <int NR>
__device__ __forceinline__ void stage_bf16(const bf16_t* g, int ld, bf16_t* lds, int tid)
{
#pragma unroll
    for (int p = 0; p < NR * 8 / 256; ++p) {
        const int gidx = p * 256 + tid;
        const int row = gidx >> 3;
        const int cp = gidx & 7;
        *(bf16x8*)(lds + row * LDS_PITCH + cp * 8) = *(const bf16x8*)(g + row * ld + cp * 8);
    }
}

__device__ __forceinline__ bf16x8 read_frag(const bf16_t* lds, int row, int cg)
{
    return *(const bf16x8*)(lds + row * LDS_PITCH + cg * 8);
}

// ---------------- fp32 -> bf16 convert ----------------
__global__ __launch_bounds__(256) void cvt_kernel(const float* __restrict__ src, bf16_t* __restrict__ dst)
{
    const size_t idx = ((size_t)blockIdx.x * 256 + threadIdx.x) * 8;
    f32x8 f = *(const f32x8*)(src + idx);
    bf16x8 v;
#pragma unroll
    for (int t = 0; t < 8; ++t) v[t] = (bf16_t)f[t];
    *(bf16x8*)(dst + idx) = v;
}

// ---------------- GEMM: C = A @ B^T, both bf16, fp32 accum ----------------
// 256x256 tile, BK=64, 512 thr = 8 waves (wm in 0..1 -> 128 rows, wn in 0..3 -> 64 cols).
// Per-wave: 8x4 16x16 fragments. 8-phase/2-tile schedule, counted vmcnt(6), raw barriers.
// MODE 0: QKV epilogue (out0=Q, out1=KT, out2=VT, all bf16). MODE 1: fp32 out + fp32 bias.
template <int MODE>
__global__ __launch_bounds__(512, 2) void gemm_bt_kernel(
    const bf16_t* __restrict__ A, const bf16_t* __restrict__ B, int K,
    void* __restrict__ out0, bf16_t* __restrict__ out1, bf16_t* __restrict__ out2,
    const float* __restrict__ bias)
{
    __shared__ __align__(16) bf16_t lds[2 * 32768];  // 128 KiB: 2 buffers x 4 regions x 8192
    const int tid = threadIdx.x;
    const int l = tid & 63, w = tid >> 6;
    const int wm = w >> 2, wn = w & 3;
    const int quad = l >> 4, r16 = l & 15;
    const int m0 = blockIdx.y * 256;
    const int n0 = blockIdx.x * 256;
    const int NT = K >> 6;  // K-tiles (assumed >= 2)

    const bf16_t* Ab = A + (size_t)m0 * K;
    const bf16_t* Bb = B + (size_t)n0 * K;

    f32x4 acc[8][4];
#pragma unroll
    for (int i = 0; i < 8; ++i)
#pragma unroll
        for (int j = 0; j < 4; ++j) acc[i][j] = zf4();

    // Prologue: tile0 fully + tile1 regions 0..2 (7 half-tiles = 14 loads/wave);
    // vmcnt(6) retires tile0, leaves 3 half-tiles in flight.
    stage_region<0>(Ab, Bb, K, 0, lds, tid);
    stage_region<1>(Ab, Bb, K, 0, lds, tid);
    stage_region<2>(Ab, Bb, K, 0, lds, tid);
    stage_region<3>(Ab, Bb, K, 0, lds, tid);
    stage_region<0>(Ab, Bb, K, 64, lds + 32768, tid);
    stage_region<1>(Ab, Bb, K, 64, lds + 32768, tid);
    stage_region<2>(Ab, Bb, K, 64, lds + 32768, tid);
    asm volatile("s_waitcnt vmcnt(6)" ::: "memory");
    __builtin_amdgcn_sched_barrier(0);
    __builtin_amdgcn_s_barrier();

    for (int t = 0; t < NT; ++t) {
        bf16_t* cb = lds + (t & 1) * 32768;
        bf16_t* nb = lds + ((t & 1) ^ 1) * 32768;

        bf16x8 bfr[4][2], af[2][2];

        // ---- phase 0: read all B frags (8) + A frags m0,m1 (4); stage next-tile region3 ----
        const bf16_t* breg = cb + (wn >> 1) * 8192;
#pragma unroll
        for (int j = 0; j < 4; ++j) {
            const int rr = (wn & 1) * 64 + j * 16 + r16;
            bfr[j][0] = rfrag(breg, rr, quad);
            bfr[j][1] = rfrag(breg, rr, 4 + quad);
        }
#pragma unroll
        for (int i2 = 0; i2 < 2; ++i2) {
            const int rr = wm * 64 + i2 * 16 + r16;
            af[i2][0] = rfrag(cb + 2 * 8192, rr, quad);
            af[i2][1] = rfrag(cb + 2 * 8192, rr, 4 + quad);
        }
        if (t + 1 < NT) stage_region<3>(Ab, Bb, K, (t + 1) * 64, nb, tid);
        __builtin_amdgcn_s_barrier();
        asm volatile("s_waitcnt lgkmcnt(0)" ::: "memory");
        __builtin_amdgcn_sched_barrier(0);
        __builtin_amdgcn_s_setprio(1);
#pragma unroll
        for (int ks = 0; ks < 2; ++ks)
#pragma unroll
            for (int i2 = 0; i2 < 2; ++i2)
#pragma unroll
                for (int j = 0; j < 4; ++j)
                    acc[i2][j] = MFMA16(af[i2][ks], bfr[j][ks], acc[i2][j]);
        __builtin_amdgcn_s_setprio(0);
        __builtin_amdgcn_s_barrier();

        // ---- phases 1..3: read A frag pair; stage tile t+2 region ph-1 into cb ----
#pragma unroll
        for (int ph = 1; ph < 4; ++ph) {
            const int mb = ph * 2;
#pragma unroll
            for (int i2 = 0; i2 < 2; ++i2) {
                const int i = mb + i2;
                const bf16_t* areg = cb + (size_t)(2 + (i >> 2)) * 8192;
                const int rr = wm * 64 + (i & 3) * 16 + r16;
                af[i2][0] = rfrag(areg, rr, quad);
                af[i2][1] = rfrag(areg, rr, 4 + quad);
            }
            if (t + 2 < NT) {
                if (ph == 1) stage_region<0>(Ab, Bb, K, (t + 2) * 64, cb, tid);
                if (ph == 2) stage_region<1>(Ab, Bb, K, (t + 2) * 64, cb, tid);
                if (ph == 3) stage_region<2>(Ab, Bb, K, (t + 2) * 64, cb, tid);
            }
            if (ph == 3) {
                // once per tile: guarantee tile t+1 fully landed; keep 3 half-tiles in flight
                if (t + 2 < NT) {
                    asm volatile("s_waitcnt vmcnt(6)" ::: "memory");
                } else if (t + 2 == NT) {
                    asm volatile("s_waitcnt vmcnt(0)" ::: "memory");
                }
                __builtin_amdgcn_sched_barrier(0);
            }
            __builtin_amdgcn_s_barrier();
            asm volatile("s_waitcnt lgkmcnt(0)" ::: "memory");
            __builtin_amdgcn_sched_barrier(0);
            __builtin_amdgcn_s_setprio(1);
#pragma unroll
            for (int ks = 0; ks < 2; ++ks)
#pragma unroll
                for (int i2 = 0; i2 < 2; ++i2)
#pragma unroll
                    for (int j = 0; j < 4; ++j)
                        acc[mb + i2][j] = MFMA16(af[i2][ks], bfr[j][ks], acc[mb + i2][j]);
            __builtin_amdgcn_s_setprio(0);
            __builtin_amdgcn_s_barrier();
        }
    }

    // C/D layout (m89/m91-verified): col = lane&15, row = quad*4 + reg
    const float scale = 0.3535533905932738f;  // 64^-0.25
#pragma unroll
    for (int i = 0; i < 8; ++i) {
        const int mbase = m0 + wm * 128 + i * 16 + quad * 4;
#pragma unroll
        for (int j = 0; j < 4; ++j) {
            const int col = n0 + wn * 64 + j * 16 + r16;
            if (MODE == 1) {
                float* yp = (float*)out0;
                const float bb = bias[col];
#pragma unroll
                for (int r = 0; r < 4; ++r)
                    yp[(size_t)(mbase + r) * 1024 + col] = acc[i][j][r] + bb;
            } else {
                const int part = col >> 10;      // 0=q, 1=k, 2=v
                const int cc = col & 1023;
                const int hh = (mbase >> 12) * 16 + (cc >> 6);  // b*16 + h
                const int d = cc & 63;
                const int ntok = mbase & 4095;
                if (part == 0) {
                    bf16_t* qp = (bf16_t*)out0 + ((size_t)hh * 4096 + ntok) * 64 + d;
#pragma unroll
                    for (int r = 0; r < 4; ++r)
                        qp[(size_t)r * 64] = (bf16_t)(feat(acc[i][j][r]) * scale);
                } else {
                    // transposed [b,h,d,n]; 4 consecutive tokens -> 8B vector store
                    bf16_t* tp = (part == 1 ? out1 : out2) + ((size_t)hh * 64 + d) * 4096 + ntok;
                    bf16x4 pk;
#pragma unroll
                    for (int r = 0; r < 4; ++r) {
                        float v = acc[i][j][r];
                        if (part == 1) v = feat(v) * scale;
                        pk[r] = (bf16_t)v;
                    }
                    *(bf16x4*)tp = pk;
                }
            }
        }
    }
}

// kv partials + ksum partials: block = (head hh, K-split ksp). Wave w owns e-rows [w*16, w*16+16).
// kvp[hh][ksp][e][d] = sum_n v[n,e] k[n,d]  (A=V-frag, B=K-frag -> C[e][d] directly).
// ksp[hh][ksp][d]    = sum_n k[n,d]         (wave 0 only: A=ones -> every C row = column sums).
__global__ __launch_bounds__(256, 2) void kv_partial_kernel(
    const bf16_t* __restrict__ KT, const bf16_t* __restrict__ VT,
    float* __restrict__ kvp, float* __restrict__ ksp_out)
{
    __shared__ __align__(16) bf16_t Ks[64 * LDS_PITCH];
    __shared__ __align__(16) bf16_t Vs[64 * LDS_PITCH];
    const int tid = threadIdx.x;
    const int l = tid & 63, w = tid >> 6;
    const int quad = l >> 4, r16 = l & 15;
    const int hh = blockIdx.x;   // 0..63 (b*16+h)
    const int ksp = blockIdx.y;  // 0..3
    const bf16_t* kb = KT + (size_t)hh * 64 * 4096 + ksp * 1024;
    const bf16_t* vb = VT + (size_t)hh * 64 * 4096 + ksp * 1024;

    bf16x8 ones;
#pragma unroll
    for (int t = 0; t < 8; ++t) ones[t] = (bf16_t)1.0f;

    f32x4 acc[4], accks[4];
#pragma unroll
    for (int j = 0; j < 4; ++j) { acc[j] = zf4(); accks[j] = zf4(); }

    for (int k0 = 0; k0 < 1024; k0 += 64) {
        stage_bf16<64>(kb + k0, 4096, Ks, tid);
        stage_bf16<64>(vb + k0, 4096, Vs, tid);
        __syncthreads();
#pragma unroll
        for (int ks = 0; ks < 2; ++ks) {
            const int cg = ks * 4 + quad;
            bf16x8 af = read_frag(Vs, w * 16 + r16, cg);  // A = V (m-index = e)
            bf16x8 bk[4];
#pragma unroll
            for (int j = 0; j < 4; ++j) bk[j] = read_frag(Ks, j * 16 + r16, cg);  // B = K (n-index = d)
#pragma unroll
            for (int j = 0; j < 4; ++j) acc[j] = MFMA16(af, bk[j], acc[j]);
            if (w == 0) {
#pragma unroll
                for (int j = 0; j < 4; ++j) accks[j] = MFMA16(ones, bk[j], accks[j]);
            }
        }
        __syncthreads();
    }

    float* ob = kvp + (size_t)(hh * 4 + ksp) * 4096;
    const int ebase = w * 16 + quad * 4;
#pragma unroll
    for (int j = 0; j < 4; ++j)
#pragma unroll
        for (int r = 0; r < 4; ++r)
            ob[(ebase + r) * 64 + j * 16 + r16] = acc[j][r];

    if (w == 0 && quad == 0) {
        float* kso = ksp_out + (size_t)(hh * 4 + ksp) * 64;
#pragma unroll
        for (int j = 0; j < 4; ++j) kso[j * 16 + r16] = accks[j][0];  // all C rows identical
    }
}

// Reduce 4 K-split partials once: kvb[hh][e][d] bf16, ksumb[hh][d] bf16.
__global__ __launch_bounds__(256) void kvfix_kernel(
    const float* __restrict__ kvp, const float* __restrict__ ksp,
    bf16_t* __restrict__ kvb, bf16_t* __restrict__ ksumb)
{
    const int hh = blockIdx.x, t = threadIdx.x;
    const float* base = kvp + (size_t)hh * 4 * 4096;
    const int off = t * 16;
    bf16x8 o[2];
#pragma unroll
    for (int c = 0; c < 4; ++c) {
        f32x4 s = *(const f32x4*)(base + off + c * 4);
        s += *(const f32x4*)(base + 4096 + off + c * 4);
        s += *(const f32x4*)(base + 8192 + off + c * 4);
        s += *(const f32x4*)(base + 12288 + off + c * 4);
#pragma unroll
        for (int r = 0; r < 4; ++r) o[c >> 1][(c & 1) * 4 + r] = (bf16_t)s[r];
    }
    *(bf16x8*)(kvb + (size_t)hh * 4096 + off) = o[0];
    *(bf16x8*)(kvb + (size_t)hh * 4096 + off + 8) = o[1];
    if (t < 64) {
        const float* kb = ksp + (size_t)hh * 4 * 64;
        ksumb[(size_t)hh * 64 + t] = (bf16_t)(kb[t] + kb[64 + t] + kb[128 + t] + kb[192 + t]);
    }
}

// att = (q @ kv) / (q . ksum + eps); block = (head, 256-token tile); wave = 64 tokens.
__global__ __launch_bounds__(256, 2) void attn_out_kernel(
    const bf16_t* __restrict__ Q, const bf16_t* __restrict__ kvb, const bf16_t* __restrict__ ksumb,
    bf16_t* __restrict__ att)
{
    __shared__ __align__(16) bf16_t kvT[64 * LDS_PITCH];  // [e][d]
    __shared__ __align__(16) bf16_t ksb[64];
    const int tid = threadIdx.x;
    const int l = tid & 63, w = tid >> 6;
    const int quad = l >> 4, r16 = l & 15;
    const int hh = blockIdx.x;
    const int b = hh >> 4, h = hh & 15;
    const int mt = blockIdx.y;  // 0..15

    {   // coalesced preamble: kvb[hh] (8KB) -> padded LDS; ksumb -> ksb
        const int e = tid >> 2, d0 = (tid & 3) * 16;
        const bf16_t* kvbh = kvb + (size_t)hh * 4096;
        *(bf16x8*)(kvT + e * LDS_PITCH + d0)     = *(const bf16x8*)(kvbh + e * 64 + d0);
        *(bf16x8*)(kvT + e * LDS_PITCH + d0 + 8) = *(const bf16x8*)(kvbh + e * 64 + d0 + 8);
        if (tid < 64) ksb[tid] = ksumb[(size_t)hh * 64 + tid];
    }
    __syncthreads();

    f32x4 acc[4][4];
    f32x4 dacc[4];
#pragma unroll
    for (int i = 0; i < 4; ++i) {
        dacc[i] = zf4();
#pragma unroll
        for (int j = 0; j < 4; ++j) acc[i][j] = zf4();
    }

    const int m0w = mt * 256 + w * 64;
    const bf16_t* qb = Q + (size_t)hh * 4096 * 64;
#pragma unroll
    for (int ks = 0; ks < 2; ++ks) {
        bf16x8 kf = *(const bf16x8*)(ksb + ks * 32 + quad * 8);
        if (r16 != 0) {
#pragma unroll
            for (int t = 0; t < 8; ++t) kf[t] = (bf16_t)0.f;
        }
        bf16x8 bfr[4];
#pragma unroll
        for (int j = 0; j < 4; ++j)
            bfr[j] = *(const bf16x8*)(kvT + (j * 16 + r16) * LDS_PITCH + ks * 32 + quad * 8);
#pragma unroll
        for (int i = 0; i < 4; ++i) {
            const bf16_t* qp = qb + (size_t)(m0w + i * 16 + r16) * 64 + ks * 32 + quad * 8;
            const bf16x8 af = *(const bf16x8*)qp;
            dacc[i] = MFMA16(af, kf, dacc[i]);
#pragma unroll
            for (int j = 0; j < 4; ++j) acc[i][j] = MFMA16(af, bfr[j], acc[i][j]);
        }
    }

#pragma unroll
    for (int i = 0; i < 4; ++i) {
        float den[4];
#pragma unroll
        for (int r = 0; r < 4; ++r)
            den[r] = __shfl(dacc[i][r], l & 48) + 1e-6f;  // quad's col-0 lane holds my rows' denom
#pragma unroll
        for (int j = 0; j < 4; ++j) {
            const size_t colb = (size_t)h * 64 + j * 16 + r16;
#pragma unroll
            for (int r = 0; r < 4; ++r) {
                const int ntok = m0w + i * 16 + quad * 4 + r;
                att[((size_t)b * 4096 + ntok) * 1024 + colb] = (bf16_t)(acc[i][j][r] / den[r]);
            }
        }
    }
}

extern "C" void kernel_launch(void* const* d_in, const int* in_sizes, int n_in,
                              void* d_out, int out_size, void* d_ws, size_t ws_size,
                              hipStream_t stream)
{
    const float* x    = (const float*)d_in[0];  // [4,4096,1024] fp32
    const float* wqkv = (const float*)d_in[1];  // [3072,1024] fp32
    const float* wout = (const float*)d_in[2];  // [1024,1024] fp32
    const float* bout = (const float*)d_in[3];  // [1024] fp32
    float* y = (float*)d_out;                   // [4,4096,1024] fp32

    char* ws = (char*)d_ws;
    bf16_t* xb    = (bf16_t*)ws;                          // 32 MiB  [16384,1024]
    bf16_t* wqkvb = (bf16_t*)(ws + (size_t)32 * 1048576); //  6 MiB  [3072,1024]
    bf16_t* woutb = (bf16_t*)(ws + (size_t)38 * 1048576); //  2 MiB  [1024,1024]
    bf16_t* Q     = (bf16_t*)(ws + (size_t)40 * 1048576); // 32 MiB  [b,h,n,d]
    bf16_t* KT    = (bf16_t*)(ws + (size_t)72 * 1048576); // 32 MiB  [b,h,d,n]
    bf16_t* VT    = (bf16_t*)(ws + (size_t)104 * 1048576);// 32 MiB  [b,h,d,n]  (end: 136 MiB)
    // aliases into xb region (xb dead after gemm<0>):
    float* kvp    = (float*)ws;                           // 4 MiB   [hh][4][e][d]
    float* ksp    = (float*)(ws + (size_t)4 * 1048576);   // 64 KiB  [hh][4][d]
    bf16_t* kvb   = (bf16_t*)(ws + (size_t)5 * 1048576);  // 512 KiB [hh][e][d]
    bf16_t* ksumb = (bf16_t*)(ws + (size_t)6 * 1048576);  // 8 KiB   [hh][d]
    bf16_t* att   = KT;                                   // KT dead after kv_partial

    cvt_kernel<<<8192, 256, 0, stream>>>(x, xb);          // 16 Mi elems
    cvt_kernel<<<1536, 256, 0, stream>>>(wqkv, wqkvb);    //  3 Mi elems
    cvt_kernel<<<512, 256, 0, stream>>>(wout, woutb);     //  1 Mi elems

    gemm_bt_kernel<0><<<dim3(12, 64), 512, 0, stream>>>(xb, wqkvb, 1024, Q, KT, VT, nullptr);
    kv_partial_kernel<<<dim3(64, 4), 256, 0, stream>>>(KT, VT, kvp, ksp);
    kvfix_kernel<<<64, 256, 0, stream>>>(kvp, ksp, kvb, ksumb);
    attn_out_kernel<<<dim3(64, 16), 256, 0, stream>>>(Q, kvb, ksumb, att);
    gemm_bt_kernel<1><<<dim3(4, 64), 512, 0, stream>>>(att, woutb, 1024, y, nullptr, nullptr, bout);
}

// Round 4
// 324.821 us; speedup vs baseline: 1.0258x; 1.0258x over previous
//
#include <hip/hip_runtime.h>
#include <hip/hip_bf16.h>
#include <cmath>

// LinearAttention: x[4,4096,1024] fp32 -> qkv -> elu+1 linear attention (16 heads, d=64) -> out proj.
// I/O fp32; internal bf16 MFMA w/ fp32 accum.
// Round 7 (resubmit x2; rounds 2-3 were GPUAcquisitionTimeout, kernel never ran):
// 256x256 8-phase GEMM with LDS as 8 DISTINCT __shared__ arrays (2 buf x {Blo,Bhi,Alo,Ahi})
// and a step-2 K-loop so every ds_read/stage targets a statically-known array. This lets the
// compiler's alias analysis prove reads don't alias in-flight global_load_lds writes, so its
// auto-inserted vmcnt hazard waits become loose (no-op) instead of vmcnt(0) drains every phase
// (the round-6 regression: MfmaUtil 22.7%, ~2345 cyc/phase). Counted vmcnt(6) once per K-tile.
// Pipeline:
//   0) cvt x->xb, w_qkv->wqkvb, w_out->woutb (bf16)
//   1) gemm_bt<0>: qkv = xb @ wqkvb^T; epilogue q->feat*scale->Q[b,h,n,d], k->KT[b,h,d,n], v->VT
//   2) kv_partial: kvp[hh][ksp][e][d] = sum_n v[n,e] k[n,d]; ksp[hh][ksp][d] = sum_n k[n,d]
//   3) kvfix: kvb[hh][e][d] (bf16) = sum_ksp kvp; ksumb[hh][d] (bf16) = sum_ksp ksp
//   4) attn_out: att = (q @ kv) / (q . ksum + eps), denom via extra MFMA column
//   5) gemm_bt<1>: y = att @ woutb^T + b_out (fp32 out)

typedef __bf16 bf16_t;
typedef __attribute__((ext_vector_type(8))) __bf16 bf16x8;
typedef __attribute__((ext_vector_type(4))) __bf16 bf16x4;
typedef __attribute__((ext_vector_type(4))) float f32x4;
typedef __attribute__((ext_vector_type(8))) float f32x8;

#define MFMA16(a, b, c) __builtin_amdgcn_mfma_f32_16x16x32_bf16((a), (b), (c), 0, 0, 0)

#define LDS_PITCH 72  // padded pitch for the simple-staging (non-GEMM) kernels

__device__ __forceinline__ f32x4 zf4() { f32x4 z; z[0] = 0.f; z[1] = 0.f; z[2] = 0.f; z[3] = 0.f; return z; }

__device__ __forceinline__ float feat(float x) { return x > 0.f ? x + 1.f : expf(x); }

// ---------------- async staging primitive ----------------
__device__ __forceinline__ void gld_lds16(const bf16_t* src, bf16_t* dst)
{
    __builtin_amdgcn_global_load_lds(
        (__attribute__((address_space(1))) void*)const_cast<bf16_t*>(src),
        (__attribute__((address_space(3))) void*)dst, 16, 0, 0);
}

// ---------------- 256x256 8-phase GEMM staging ----------------
// One panel = 128 rows x 64 bf16 (16 KiB), XOR-swizzled by granule: LDS granule (rr,p)
// holds global granule (rr, p ^ (rr&7)). 512 threads, 2 global_load_lds per wave per panel.
// RT: 0 = B rows 0-127, 1 = B rows 128-255, 2 = A rows 0-63 & 128-191, 3 = A rows 64-127 & 192-255.
template <int RT>
__device__ __forceinline__ const bf16_t* panel_src(const bf16_t* Ab, const bf16_t* Bb, int K, int rr)
{
    if (RT == 0) return Bb + (size_t)rr * K;
    if (RT == 1) return Bb + (size_t)(128 + rr) * K;
    if (RT == 2) return Ab + (size_t)(rr + (rr & 64)) * K;
    return Ab + (size_t)(64 + rr + (rr & 64)) * K;
}

template <int RT>
__device__ __forceinline__ void stage_panel(const bf16_t* Ab, const bf16_t* Bb, int K,
                                            int koff, bf16_t* dst, int tid)
{
    const int w = tid >> 6, l = tid & 63;
#pragma unroll
    for (int p = 0; p < 2; ++p) {
        const int chunk = w * 2 + p;          // wave-uniform, 0..15
        const int gidx = chunk * 64 + l;      // granule 0..1023
        const int rr = gidx >> 3;             // panel row 0..127
        const int c = (gidx & 7) ^ (rr & 7);  // pre-swizzled source granule
        gld_lds16(panel_src<RT>(Ab, Bb, K, rr) + koff + c * 8, dst + chunk * 512);
    }
}

// Fragment read from a swizzled panel (64-elem pitch): 2-way LDS aliasing only (free, m136).
__device__ __forceinline__ bf16x8 rfrag(const bf16_t* panel, int rr, int cg)
{
    const int sw = cg ^ (rr & 7);
    return *(const bf16x8*)(panel + rr * 64 + sw * 8);
}

// ---------------- simple staging (middle kernels) ----------------
template <int NR>
__device__ __forceinline__ void stage_bf16(const bf16_t* g, int ld, bf16_t* lds, int tid)
{
#pragma unroll
    for (int p = 0; p < NR * 8 / 256; ++p) {
        const int gidx = p * 256 + tid;
        const int row = gidx >> 3;
        const int cp = gidx & 7;
        *(bf16x8*)(lds + row * LDS_PITCH + cp * 8) = *(const bf16x8*)(g + row * ld + cp * 8);
    }
}

__device__ __forceinline__ bf16x8 read_frag(const bf16_t* lds, int row, int cg)
{
    return *(const bf16x8*)(lds + row * LDS_PITCH + cg * 8);
}

// ---------------- fp32 -> bf16 convert ----------------
__global__ __launch_bounds__(256) void cvt_kernel(const float* __restrict__ src, bf16_t* __restrict__ dst)
{
    const size_t idx = ((size_t)blockIdx.x * 256 + threadIdx.x) * 8;
    f32x8 f = *(const f32x8*)(src + idx);
    bf16x8 v;
#pragma unroll
    for (int t = 0; t < 8; ++t) v[t] = (bf16_t)f[t];
    *(bf16x8*)(dst + idx) = v;
}

#define GBAR() __builtin_amdgcn_s_barrier()
#define WAITL() do { asm volatile("s_waitcnt lgkmcnt(0)" ::: "memory"); \
                     __builtin_amdgcn_sched_barrier(0); } while (0)
#define VMC6() do { asm volatile("s_waitcnt vmcnt(6)" ::: "memory"); \
                    __builtin_amdgcn_sched_barrier(0); } while (0)
#define VMC0() do { asm volatile("s_waitcnt vmcnt(0)" ::: "memory"); \
                    __builtin_amdgcn_sched_barrier(0); } while (0)

// ---------------- GEMM: C = A @ B^T, both bf16, fp32 accum ----------------
// 256x256 tile, BK=64, 512 thr = 8 waves (wm 0..1 -> 128 rows, wn 0..3 -> 64 cols).
// Per-wave: 8x4 16x16 fragments. Step-2 K-loop, 8 phases/iter, counted vmcnt, raw barriers.
// Requires NT = K/64 even and >= 4 (K=1024 here -> NT=16).
// MODE 0: QKV epilogue (out0=Q, out1=KT, out2=VT, all bf16). MODE 1: fp32 out + fp32 bias.
template <int MODE>
__global__ __launch_bounds__(512, 2) void gemm_bt_kernel(
    const bf16_t* __restrict__ A, const bf16_t* __restrict__ B, int K,
    void* __restrict__ out0, bf16_t* __restrict__ out1, bf16_t* __restrict__ out2,
    const float* __restrict__ bias)
{
    // 8 distinct arrays -> static alias disambiguation for ds_read vs in-flight LDS-DMA writes.
    __shared__ __align__(16) bf16_t B0a[8192], B0b[8192], A0a[8192], A0b[8192];
    __shared__ __align__(16) bf16_t B1a[8192], B1b[8192], A1a[8192], A1b[8192];
    const int tid = threadIdx.x;
    const int l = tid & 63, w = tid >> 6;
    const int wm = w >> 2, wn = w & 3;
    const int quad = l >> 4, r16 = l & 15;
    const int m0 = blockIdx.y * 256;
    const int n0 = blockIdx.x * 256;
    const int NT = K >> 6;  // K-tiles; even, >= 4

    const bf16_t* Ab = A + (size_t)m0 * K;
    const bf16_t* Bb = B + (size_t)n0 * K;

    f32x4 acc[8][4];
#pragma unroll
    for (int i = 0; i < 8; ++i)
#pragma unroll
        for (int j = 0; j < 4; ++j) acc[i][j] = zf4();

    bf16x8 bfr[4][2], af[2][2];

    auto loadB = [&](const bf16_t* Blo, const bf16_t* Bhi) {
        const bf16_t* breg = (wn & 2) ? Bhi : Blo;
#pragma unroll
        for (int j = 0; j < 4; ++j) {
            const int rr = (wn & 1) * 64 + j * 16 + r16;
            bfr[j][0] = rfrag(breg, rr, quad);
            bfr[j][1] = rfrag(breg, rr, 4 + quad);
        }
    };
    auto loadA = [&](const bf16_t* areg, int fr) {  // fr in {0,2}: frag pair within panel
#pragma unroll
        for (int i2 = 0; i2 < 2; ++i2) {
            const int rr = wm * 64 + (fr + i2) * 16 + r16;
            af[i2][0] = rfrag(areg, rr, quad);
            af[i2][1] = rfrag(areg, rr, 4 + quad);
        }
    };
    auto mfma8 = [&](int mb) {
        __builtin_amdgcn_s_setprio(1);
#pragma unroll
        for (int ks = 0; ks < 2; ++ks)
#pragma unroll
            for (int i2 = 0; i2 < 2; ++i2)
#pragma unroll
                for (int j = 0; j < 4; ++j)
                    acc[mb + i2][j] = MFMA16(af[i2][ks], bfr[j][ks], acc[mb + i2][j]);
        __builtin_amdgcn_s_setprio(0);
    };

    // Prologue: tile0 all 4 panels + tile1 {Blo,Bhi,Alo} = 14 loads/wave;
    // vmcnt(6) retires tile0's 8, leaves tile1's 6 in flight.
    stage_panel<0>(Ab, Bb, K, 0, B0a, tid);
    stage_panel<1>(Ab, Bb, K, 0, B0b, tid);
    stage_panel<2>(Ab, Bb, K, 0, A0a, tid);
    stage_panel<3>(Ab, Bb, K, 0, A0b, tid);
    stage_panel<0>(Ab, Bb, K, 64, B1a, tid);
    stage_panel<1>(Ab, Bb, K, 64, B1b, tid);
    stage_panel<2>(Ab, Bb, K, 64, A1a, tid);
    VMC6();
    GBAR();

    for (int t = 0; t < NT; t += 2) {
        const int k2 = (t + 2) * 64, k3 = (t + 3) * 64;
        const bool p2 = (t + 2) < NT, p3 = (t + 3) < NT;

        // ======== tile t (buffer 0) ========
        // ph0: all B frags + A frags 0-1; stage tile(t+1) Ahi (its panels Blo/Bhi/Alo already in flight)
        loadB(B0a, B0b); loadA(A0a, 0);
        stage_panel<3>(Ab, Bb, K, (t + 1) * 64, A1b, tid);
        GBAR(); WAITL(); mfma8(0); GBAR();
        // ph1: A frags 2-3; B0a consumed in ph0 -> restage for t+2
        loadA(A0a, 2);
        if (p2) stage_panel<0>(Ab, Bb, K, k2, B0a, tid);
        GBAR(); WAITL(); mfma8(2); GBAR();
        // ph2: A frags 4-5; restage B0b for t+2
        loadA(A0b, 0);
        if (p2) stage_panel<1>(Ab, Bb, K, k2, B0b, tid);
        GBAR(); WAITL(); mfma8(4); GBAR();
        // ph3: A frags 6-7; restage A0a for t+2; once-per-tile wait retires tile t+1's panels
        loadA(A0b, 2);
        if (p2) { stage_panel<2>(Ab, Bb, K, k2, A0a, tid); VMC6(); }
        else    { VMC0(); }
        GBAR(); WAITL(); mfma8(6); GBAR();

        // ======== tile t+1 (buffer 1) ========
        // ph4: all B frags + A frags 0-1; stage tile(t+2) Ahi
        loadB(B1a, B1b); loadA(A1a, 0);
        if (p2) stage_panel<3>(Ab, Bb, K, k2, A0b, tid);
        GBAR(); WAITL(); mfma8(0); GBAR();
        // ph5: A frags 2-3; restage B1a for t+3
        loadA(A1a, 2);
        if (p3) stage_panel<0>(Ab, Bb, K, k3, B1a, tid);
        GBAR(); WAITL(); mfma8(2); GBAR();
        // ph6: A frags 4-5; restage B1b for t+3
        loadA(A1b, 0);
        if (p3) stage_panel<1>(Ab, Bb, K, k3, B1b, tid);
        GBAR(); WAITL(); mfma8(4); GBAR();
        // ph7: A frags 6-7; restage A1a for t+3; once-per-tile wait retires tile t+2's panels
        loadA(A1b, 2);
        if (p3) { stage_panel<2>(Ab, Bb, K, k3, A1a, tid); VMC6(); }
        else    { VMC0(); }
        GBAR(); WAITL(); mfma8(6); GBAR();
    }

    // C/D layout (m89/m91-verified): col = lane&15, row = quad*4 + reg
    const float scale = 0.3535533905932738f;  // 64^-0.25
#pragma unroll
    for (int i = 0; i < 8; ++i) {
        const int mbase = m0 + wm * 128 + i * 16 + quad * 4;
#pragma unroll
        for (int j = 0; j < 4; ++j) {
            const int col = n0 + wn * 64 + j * 16 + r16;
            if (MODE == 1) {
                float* yp = (float*)out0;
                const float bb = bias[col];
#pragma unroll
                for (int r = 0; r < 4; ++r)
                    yp[(size_t)(mbase + r) * 1024 + col] = acc[i][j][r] + bb;
            } else {
                const int part = col >> 10;      // 0=q, 1=k, 2=v
                const int cc = col & 1023;
                const int hh = (mbase >> 12) * 16 + (cc >> 6);  // b*16 + h
                const int d = cc & 63;
                const int ntok = mbase & 4095;
                if (part == 0) {
                    bf16_t* qp = (bf16_t*)out0 + ((size_t)hh * 4096 + ntok) * 64 + d;
#pragma unroll
                    for (int r = 0; r < 4; ++r)
                        qp[(size_t)r * 64] = (bf16_t)(feat(acc[i][j][r]) * scale);
                } else {
                    // transposed [b,h,d,n]; 4 consecutive tokens -> 8B vector store
                    bf16_t* tp = (part == 1 ? out1 : out2) + ((size_t)hh * 64 + d) * 4096 + ntok;
                    bf16x4 pk;
#pragma unroll
                    for (int r = 0; r < 4; ++r) {
                        float v = acc[i][j][r];
                        if (part == 1) v = feat(v) * scale;
                        pk[r] = (bf16_t)v;
                    }
                    *(bf16x4*)tp = pk;
                }
            }
        }
    }
}

// kv partials + ksum partials: block = (head hh, K-split ksp). Wave w owns e-rows [w*16, w*16+16).
// kvp[hh][ksp][e][d] = sum_n v[n,e] k[n,d]  (A=V-frag, B=K-frag -> C[e][d] directly).
// ksp[hh][ksp][d]    = sum_n k[n,d]         (wave 0 only: A=ones -> every C row = column sums).
__global__ __launch_bounds__(256, 2) void kv_partial_kernel(
    const bf16_t* __restrict__ KT, const bf16_t* __restrict__ VT,
    float* __restrict__ kvp, float* __restrict__ ksp_out)
{
    __shared__ __align__(16) bf16_t Ks[64 * LDS_PITCH];
    __shared__ __align__(16) bf16_t Vs[64 * LDS_PITCH];
    const int tid = threadIdx.x;
    const int l = tid & 63, w = tid >> 6;
    const int quad = l >> 4, r16 = l & 15;
    const int hh = blockIdx.x;   // 0..63 (b*16+h)
    const int ksp = blockIdx.y;  // 0..3
    const bf16_t* kb = KT + (size_t)hh * 64 * 4096 + ksp * 1024;
    const bf16_t* vb = VT + (size_t)hh * 64 * 4096 + ksp * 1024;

    bf16x8 ones;
#pragma unroll
    for (int t = 0; t < 8; ++t) ones[t] = (bf16_t)1.0f;

    f32x4 acc[4], accks[4];
#pragma unroll
    for (int j = 0; j < 4; ++j) { acc[j] = zf4(); accks[j] = zf4(); }

    for (int k0 = 0; k0 < 1024; k0 += 64) {
        stage_bf16<64>(kb + k0, 4096, Ks, tid);
        stage_bf16<64>(vb + k0, 4096, Vs, tid);
        __syncthreads();
#pragma unroll
        for (int ks = 0; ks < 2; ++ks) {
            const int cg = ks * 4 + quad;
            bf16x8 af = read_frag(Vs, w * 16 + r16, cg);  // A = V (m-index = e)
            bf16x8 bk[4];
#pragma unroll
            for (int j = 0; j < 4; ++j) bk[j] = read_frag(Ks, j * 16 + r16, cg);  // B = K (n-index = d)
#pragma unroll
            for (int j = 0; j < 4; ++j) acc[j] = MFMA16(af, bk[j], acc[j]);
            if (w == 0) {
#pragma unroll
                for (int j = 0; j < 4; ++j) accks[j] = MFMA16(ones, bk[j], accks[j]);
            }
        }
        __syncthreads();
    }

    float* ob = kvp + (size_t)(hh * 4 + ksp) * 4096;
    const int ebase = w * 16 + quad * 4;
#pragma unroll
    for (int j = 0; j < 4; ++j)
#pragma unroll
        for (int r = 0; r < 4; ++r)
            ob[(ebase + r) * 64 + j * 16 + r16] = acc[j][r];

    if (w == 0 && quad == 0) {
        float* kso = ksp_out + (size_t)(hh * 4 + ksp) * 64;
#pragma unroll
        for (int j = 0; j < 4; ++j) kso[j * 16 + r16] = accks[j][0];  // all C rows identical
    }
}

// Reduce 4 K-split partials once: kvb[hh][e][d] bf16, ksumb[hh][d] bf16.
__global__ __launch_bounds__(256) void kvfix_kernel(
    const float* __restrict__ kvp, const float* __restrict__ ksp,
    bf16_t* __restrict__ kvb, bf16_t* __restrict__ ksumb)
{
    const int hh = blockIdx.x, t = threadIdx.x;
    const float* base = kvp + (size_t)hh * 4 * 4096;
    const int off = t * 16;
    bf16x8 o[2];
#pragma unroll
    for (int c = 0; c < 4; ++c) {
        f32x4 s = *(const f32x4*)(base + off + c * 4);
        s += *(const f32x4*)(base + 4096 + off + c * 4);
        s += *(const f32x4*)(base + 8192 + off + c * 4);
        s += *(const f32x4*)(base + 12288 + off + c * 4);
#pragma unroll
        for (int r = 0; r < 4; ++r) o[c >> 1][(c & 1) * 4 + r] = (bf16_t)s[r];
    }
    *(bf16x8*)(kvb + (size_t)hh * 4096 + off) = o[0];
    *(bf16x8*)(kvb + (size_t)hh * 4096 + off + 8) = o[1];
    if (t < 64) {
        const float* kb = ksp + (size_t)hh * 4 * 64;
        ksumb[(size_t)hh * 64 + t] = (bf16_t)(kb[t] + kb[64 + t] + kb[128 + t] + kb[192 + t]);
    }
}

// att = (q @ kv) / (q . ksum + eps); block = (head, 256-token tile); wave = 64 tokens.
__global__ __launch_bounds__(256, 2) void attn_out_kernel(
    const bf16_t* __restrict__ Q, const bf16_t* __restrict__ kvb, const bf16_t* __restrict__ ksumb,
    bf16_t* __restrict__ att)
{
    __shared__ __align__(16) bf16_t kvT[64 * LDS_PITCH];  // [e][d]
    __shared__ __align__(16) bf16_t ksb[64];
    const int tid = threadIdx.x;
    const int l = tid & 63, w = tid >> 6;
    const int quad = l >> 4, r16 = l & 15;
    const int hh = blockIdx.x;
    const int b = hh >> 4, h = hh & 15;
    const int mt = blockIdx.y;  // 0..15

    {   // coalesced preamble: kvb[hh] (8KB) -> padded LDS; ksumb -> ksb
        const int e = tid >> 2, d0 = (tid & 3) * 16;
        const bf16_t* kvbh = kvb + (size_t)hh * 4096;
        *(bf16x8*)(kvT + e * LDS_PITCH + d0)     = *(const bf16x8*)(kvbh + e * 64 + d0);
        *(bf16x8*)(kvT + e * LDS_PITCH + d0 + 8) = *(const bf16x8*)(kvbh + e * 64 + d0 + 8);
        if (tid < 64) ksb[tid] = ksumb[(size_t)hh * 64 + tid];
    }
    __syncthreads();

    f32x4 acc[4][4];
    f32x4 dacc[4];
#pragma unroll
    for (int i = 0; i < 4; ++i) {
        dacc[i] = zf4();
#pragma unroll
        for (int j = 0; j < 4; ++j) acc[i][j] = zf4();
    }

    const int m0w = mt * 256 + w * 64;
    const bf16_t* qb = Q + (size_t)hh * 4096 * 64;
#pragma unroll
    for (int ks = 0; ks < 2; ++ks) {
        bf16x8 kf = *(const bf16x8*)(ksb + ks * 32 + quad * 8);
        if (r16 != 0) {
#pragma unroll
            for (int t = 0; t < 8; ++t) kf[t] = (bf16_t)0.f;
        }
        bf16x8 bfr[4];
#pragma unroll
        for (int j = 0; j < 4; ++j)
            bfr[j] = *(const bf16x8*)(kvT + (j * 16 + r16) * LDS_PITCH + ks * 32 + quad * 8);
#pragma unroll
        for (int i = 0; i < 4; ++i) {
            const bf16_t* qp = qb + (size_t)(m0w + i * 16 + r16) * 64 + ks * 32 + quad * 8;
            const bf16x8 af = *(const bf16x8*)qp;
            dacc[i] = MFMA16(af, kf, dacc[i]);
#pragma unroll
            for (int j = 0; j < 4; ++j) acc[i][j] = MFMA16(af, bfr[j], acc[i][j]);
        }
    }

#pragma unroll
    for (int i = 0; i < 4; ++i) {
        float den[4];
#pragma unroll
        for (int r = 0; r < 4; ++r)
            den[r] = __shfl(dacc[i][r], l & 48) + 1e-6f;  // quad's col-0 lane holds my rows' denom
#pragma unroll
        for (int j = 0; j < 4; ++j) {
            const size_t colb = (size_t)h * 64 + j * 16 + r16;
#pragma unroll
            for (int r = 0; r < 4; ++r) {
                const int ntok = m0w + i * 16 + quad * 4 + r;
                att[((size_t)b * 4096 + ntok) * 1024 + colb] = (bf16_t)(acc[i][j][r] / den[r]);
            }
        }
    }
}

extern "C" void kernel_launch(void* const* d_in, const int* in_sizes, int n_in,
                              void* d_out, int out_size, void* d_ws, size_t ws_size,
                              hipStream_t stream)
{
    const float* x    = (const float*)d_in[0];  // [4,4096,1024] fp32
    const float* wqkv = (const float*)d_in[1];  // [3072,1024] fp32
    const float* wout = (const float*)d_in[2];  // [1024,1024] fp32
    const float* bout = (const float*)d_in[3];  // [1024] fp32
    float* y = (float*)d_out;                   // [4,4096,1024] fp32

    char* ws = (char*)d_ws;
    bf16_t* xb    = (bf16_t*)ws;                          // 32 MiB  [16384,1024]
    bf16_t* wqkvb = (bf16_t*)(ws + (size_t)32 * 1048576); //  6 MiB  [3072,1024]
    bf16_t* woutb = (bf16_t*)(ws + (size_t)38 * 1048576); //  2 MiB  [1024,1024]
    bf16_t* Q     = (bf16_t*)(ws + (size_t)40 * 1048576); // 32 MiB  [b,h,n,d]
    bf16_t* KT    = (bf16_t*)(ws + (size_t)72 * 1048576); // 32 MiB  [b,h,d,n]
    bf16_t* VT    = (bf16_t*)(ws + (size_t)104 * 1048576);// 32 MiB  [b,h,d,n]  (end: 136 MiB)
    // aliases into xb region (xb dead after gemm<0>):
    float* kvp    = (float*)ws;                           // 4 MiB   [hh][4][e][d]
    float* ksp    = (float*)(ws + (size_t)4 * 1048576);   // 64 KiB  [hh][4][d]
    bf16_t* kvb   = (bf16_t*)(ws + (size_t)5 * 1048576);  // 512 KiB [hh][e][d]
    bf16_t* ksumb = (bf16_t*)(ws + (size_t)6 * 1048576);  // 8 KiB   [hh][d]
    bf16_t* att   = KT;                                   // KT dead after kv_partial

    cvt_kernel<<<8192, 256, 0, stream>>>(x, xb);          // 16 Mi elems
    cvt_kernel<<<1536, 256, 0, stream>>>(wqkv, wqkvb);    //  3 Mi elems
    cvt_kernel<<<512, 256, 0, stream>>>(wout, woutb);     //  1 Mi elems

    gemm_bt_kernel<0><<<dim3(12, 64), 512, 0, stream>>>(xb, wqkvb, 1024, Q, KT, VT, nullptr);
    kv_partial_kernel<<<dim3(64, 4), 256, 0, stream>>>(KT, VT, kvp, ksp);
    kvfix_kernel<<<64, 256, 0, stream>>>(kvp, ksp, kvb, ksumb);
    attn_out_kernel<<<dim3(64, 16), 256, 0, stream>>>(Q, kvb, ksumb, att);
    gemm_bt_kernel<1><<<dim3(4, 64), 512, 0, stream>>>(att, woutb, 1024, y, nullptr, nullptr, bout);
}